// Round 1
// baseline (7330.650 us; speedup 1.0000x reference)
//
#include <hip/hip_runtime.h>
#include <math.h>

#define N1 4096
#define N2 65536
#define DIM 1024
#define KNN 4
#define CSPLIT 32                       // column splits for partial top-k
#define BM 128
#define BN 128
#define BK 16
#define LSTR 132                        // BM + 4 pad (breaks LDS store conflicts)
#define COLS_PER_SPLIT (N2 / CSPLIT)    // 2048
#define TILES_PER_SPLIT (COLS_PER_SPLIT / BN)  // 16

// ---------------- Kernel 0: 1/|s_j| for all synth rows ----------------
// One wave (64 lanes) per vector; lane l reads float4s at dims 4l, 4l+256, ...
__global__ void invnorm_kernel(const float* __restrict__ synth,
                               float* __restrict__ invn) {
    const int lane = threadIdx.x & 63;
    const int wv = threadIdx.x >> 6;
    const int v = blockIdx.x * 4 + wv;
    const float* row = synth + (size_t)v * DIM;
    float ss = 0.f;
#pragma unroll
    for (int i = 0; i < 4; ++i) {
        float4 x = *(const float4*)(row + lane * 4 + i * 256);
        ss += x.x * x.x + x.y * x.y + x.z * x.z + x.w * x.w;
    }
#pragma unroll
    for (int off = 32; off > 0; off >>= 1) ss += __shfl_xor(ss, off, 64);
    // exact-ish 1/sqrt (NOT rsqrtf: its ~1e-5 rel error could flip top-k)
    if (lane == 0) invn[v] = 1.0f / sqrtf(ss);
}

// ---------------- Kernel 1: fused SGEMM + per-row running top-4 ----------------
// Block: 128 query rows x 2048 synth cols (16 tiles of 128), K = 1024.
// 256 threads, 8x8 micro-tile each. Running top-4 held by threads 0..127
// (thread r owns query row rowBase+r) across the 16 col-tiles.
__global__ __launch_bounds__(256) void score_topk_kernel(
    const float* __restrict__ query, const float* __restrict__ synth,
    const float* __restrict__ invn, float* __restrict__ pScore,
    int* __restrict__ pIdx) {
    __shared__ float As[BK][LSTR];
    __shared__ float Bs[BK][LSTR];
    __shared__ float Sc[BM][65];        // 65 = 64+1 pad -> conflict-free row scans
    __shared__ float invLds[BN];

    const int tid = threadIdx.x;
    const int tx = tid & 15;            // col group (x8)
    const int ty = tid >> 4;            // row group (x8)
    const int rowBase = blockIdx.y * BM;
    const int colSplit = blockIdx.x;
    const int colStart = colSplit * COLS_PER_SPLIT;

    const int lr = tid >> 2;            // staging row 0..63 (+64 for second half)
    const int lk = (tid & 3) * 4;       // staging k offset

    float tv0 = -1e30f, tv1 = -1e30f, tv2 = -1e30f, tv3 = -1e30f;
    int ti0 = 0, ti1 = 0, ti2 = 0, ti3 = 0;

    for (int tile = 0; tile < TILES_PER_SPLIT; ++tile) {
        const int colBase = colStart + tile * BN;
        float acc[8][8];
#pragma unroll
        for (int i = 0; i < 8; ++i)
#pragma unroll
            for (int j = 0; j < 8; ++j) acc[i][j] = 0.f;

        __syncthreads();                 // previous tile's scan phase done
        if (tid < BN) invLds[tid] = invn[colBase + tid];

        for (int kk = 0; kk < DIM; kk += BK) {
            float4 a0 = *(const float4*)(query + (size_t)(rowBase + lr) * DIM + kk + lk);
            float4 a1 = *(const float4*)(query + (size_t)(rowBase + lr + 64) * DIM + kk + lk);
            float4 b0 = *(const float4*)(synth + (size_t)(colBase + lr) * DIM + kk + lk);
            float4 b1 = *(const float4*)(synth + (size_t)(colBase + lr + 64) * DIM + kk + lk);
            __syncthreads();             // LDS free (previous compute done)
            As[lk + 0][lr] = a0.x; As[lk + 1][lr] = a0.y;
            As[lk + 2][lr] = a0.z; As[lk + 3][lr] = a0.w;
            As[lk + 0][lr + 64] = a1.x; As[lk + 1][lr + 64] = a1.y;
            As[lk + 2][lr + 64] = a1.z; As[lk + 3][lr + 64] = a1.w;
            Bs[lk + 0][lr] = b0.x; Bs[lk + 1][lr] = b0.y;
            Bs[lk + 2][lr] = b0.z; Bs[lk + 3][lr] = b0.w;
            Bs[lk + 0][lr + 64] = b1.x; Bs[lk + 1][lr + 64] = b1.y;
            Bs[lk + 2][lr + 64] = b1.z; Bs[lk + 3][lr + 64] = b1.w;
            __syncthreads();
#pragma unroll
            for (int k = 0; k < BK; ++k) {
                float ar[8], br[8];
                *(float4*)&ar[0] = *(const float4*)&As[k][ty * 8];
                *(float4*)&ar[4] = *(const float4*)&As[k][ty * 8 + 4];
                *(float4*)&br[0] = *(const float4*)&Bs[k][tx * 8];
                *(float4*)&br[4] = *(const float4*)&Bs[k][tx * 8 + 4];
#pragma unroll
                for (int i = 0; i < 8; ++i)
#pragma unroll
                    for (int j = 0; j < 8; ++j)
                        acc[i][j] = fmaf(ar[i], br[j], acc[i][j]);
            }
        }

        // score = dot * invnorm; stage 64 cols at a time through LDS, scan.
#pragma unroll
        for (int h = 0; h < 2; ++h) {
            __syncthreads();
            if ((tx >> 3) == h) {
#pragma unroll
                for (int i = 0; i < 8; ++i)
#pragma unroll
                    for (int j = 0; j < 8; ++j)
                        Sc[ty * 8 + i][(tx & 7) * 8 + j] =
                            acc[i][j] * invLds[tx * 8 + j];
            }
            __syncthreads();
            if (tid < BM) {
                for (int c = 0; c < 64; ++c) {
                    const float v = Sc[tid][c];
                    float mn = tv0; int mi = 0;
                    if (tv1 < mn) { mn = tv1; mi = 1; }
                    if (tv2 < mn) { mn = tv2; mi = 2; }
                    if (tv3 < mn) { mn = tv3; mi = 3; }
                    if (v > mn) {
                        const int idx = colBase + h * 64 + c;
                        if (mi == 0)      { tv0 = v; ti0 = idx; }
                        else if (mi == 1) { tv1 = v; ti1 = idx; }
                        else if (mi == 2) { tv2 = v; ti2 = idx; }
                        else              { tv3 = v; ti3 = idx; }
                    }
                }
            }
        }
    }

    if (tid < BM) {
        const int row = rowBase + tid;
        const size_t base = ((size_t)row * CSPLIT + colSplit) * KNN;
        pScore[base + 0] = tv0; pIdx[base + 0] = ti0;
        pScore[base + 1] = tv1; pIdx[base + 1] = ti1;
        pScore[base + 2] = tv2; pIdx[base + 2] = ti2;
        pScore[base + 3] = tv3; pIdx[base + 3] = ti3;
    }
}

// ---------------- Kernel 2: merge partials, gather-mean, repeat x2 ----------------
__global__ void gather_kernel(const float* __restrict__ synth,
                              const float* __restrict__ pScore,
                              const int* __restrict__ pIdx,
                              float* __restrict__ out) {
    const int row = blockIdx.x;
    __shared__ int sIdx[KNN];
    if (threadIdx.x == 0) {
        float bv0 = -1e30f, bv1 = -1e30f, bv2 = -1e30f, bv3 = -1e30f;
        int bi0 = 0, bi1 = 0, bi2 = 0, bi3 = 0;
        const float* ps = pScore + (size_t)row * CSPLIT * KNN;
        const int* pi = pIdx + (size_t)row * CSPLIT * KNN;
        for (int c = 0; c < CSPLIT * KNN; ++c) {
            const float v = ps[c];
            float mn = bv0; int mi = 0;
            if (bv1 < mn) { mn = bv1; mi = 1; }
            if (bv2 < mn) { mn = bv2; mi = 2; }
            if (bv3 < mn) { mn = bv3; mi = 3; }
            if (v > mn) {
                const int idx = pi[c];
                if (mi == 0)      { bv0 = v; bi0 = idx; }
                else if (mi == 1) { bv1 = v; bi1 = idx; }
                else if (mi == 2) { bv2 = v; bi2 = idx; }
                else              { bv3 = v; bi3 = idx; }
            }
        }
        sIdx[0] = bi0; sIdx[1] = bi1; sIdx[2] = bi2; sIdx[3] = bi3;
    }
    __syncthreads();
    const int d = threadIdx.x * 4;      // 256 threads x float4 = 1024 dims
    float4 s = make_float4(0.f, 0.f, 0.f, 0.f);
#pragma unroll
    for (int m = 0; m < KNN; ++m) {
        float4 x = *(const float4*)(synth + (size_t)sIdx[m] * DIM + d);
        s.x += x.x; s.y += x.y; s.z += x.z; s.w += x.w;
    }
    s.x *= 0.25f; s.y *= 0.25f; s.z *= 0.25f; s.w *= 0.25f;
    *(float4*)(out + (size_t)(2 * row) * DIM + d) = s;
    *(float4*)(out + (size_t)(2 * row + 1) * DIM + d) = s;
}

extern "C" void kernel_launch(void* const* d_in, const int* in_sizes, int n_in,
                              void* d_out, int out_size, void* d_ws, size_t ws_size,
                              hipStream_t stream) {
    const float* query = (const float*)d_in[0];   // (N1, DIM) fp32
    const float* synth = (const float*)d_in[1];   // (N2, DIM) fp32
    float* out = (float*)d_out;                   // (2*N1, DIM) fp32

    char* ws = (char*)d_ws;
    float* invn = (float*)ws;                                        // N2 floats
    float* pScore = (float*)(ws + (size_t)N2 * 4);                   // N1*CSPLIT*KNN floats
    int* pIdx = (int*)(ws + (size_t)N2 * 4 + (size_t)N1 * CSPLIT * KNN * 4);

    invnorm_kernel<<<N2 / 4, 256, 0, stream>>>(synth, invn);

    dim3 g1(CSPLIT, N1 / BM);
    score_topk_kernel<<<g1, 256, 0, stream>>>(query, synth, invn, pScore, pIdx);

    gather_kernel<<<N1, 256, 0, stream>>>(synth, pScore, pIdx, out);
}

// Round 2
// 1447.645 us; speedup vs baseline: 5.0638x; 5.0638x over previous
//
#include <hip/hip_runtime.h>
#include <math.h>
#include <stdint.h>

#define N1 4096
#define N2 65536
#define DIM 1024
#define KNN 4
#define CSPLIT 32
#define BM 128
#define BN 128
#define COLS_PER_SPLIT (N2 / CSPLIT)          // 2048
#define TILES_PER_SPLIT (COLS_PER_SPLIT / BN) // 16
#define NCAND 16
#define SCSTR 68                               // Sc stride: 68 floats -> 2-way banks on writes

typedef __attribute__((ext_vector_type(8))) short short8;
typedef __attribute__((ext_vector_type(4))) float f32x4;

#define GLDS16(g, l)                                                          \
    __builtin_amdgcn_global_load_lds(                                         \
        (const __attribute__((address_space(1))) void*)(g),                   \
        (__attribute__((address_space(3))) void*)(l), 16, 0, 0)

__device__ __forceinline__ unsigned short f2bf(float f) {
    union { float f; uint32_t u; } v; v.f = f;
    uint32_t r = v.u + 0x7fffu + ((v.u >> 16) & 1u);   // RNE truncate to bf16
    return (unsigned short)(r >> 16);
}

// ---------------- fp32 -> bf16 with per-row XOR chunk swizzle ----------------
// dst[row][g] = src[row][(g & ~3) | ((g&3) ^ s(row))],  s(r) = (r&3)^((r>>2)&3).
// A linear 64B global->LDS copy then lands fragments so ds_read_b128 is
// conflict-free (each 16-lane q-group spreads 2 lanes per bank-quad).
__global__ void convert_swz_kernel(const float* __restrict__ src,
                                   unsigned short* __restrict__ dst) {
    const int c = blockIdx.x * 256 + threadIdx.x;   // 16B-chunk id
    const int row = c >> 7;                          // DIM/8 = 128 chunks per row
    const int g = c & 127;
    const int s = (row & 3) ^ ((row >> 2) & 3);
    const int gs = (g & ~3) | ((g & 3) ^ s);
    const float* p = src + ((size_t)row << 10) + (gs << 3);
    const float4 a = *(const float4*)p;
    const float4 b = *(const float4*)(p + 4);
    short8 o;
    o[0] = (short)f2bf(a.x); o[1] = (short)f2bf(a.y);
    o[2] = (short)f2bf(a.z); o[3] = (short)f2bf(a.w);
    o[4] = (short)f2bf(b.x); o[5] = (short)f2bf(b.y);
    o[6] = (short)f2bf(b.z); o[7] = (short)f2bf(b.w);
    *(short8*)(dst + ((size_t)row << 10) + (g << 3)) = o;
}

// ---------------- 1/|s_j| (exact fp32, from original data) ----------------
__global__ void invnorm_kernel(const float* __restrict__ synth,
                               float* __restrict__ invn) {
    const int lane = threadIdx.x & 63;
    const int wv = threadIdx.x >> 6;
    const int v = blockIdx.x * 4 + wv;
    const float* row = synth + (size_t)v * DIM;
    float ss = 0.f;
#pragma unroll
    for (int i = 0; i < 4; ++i) {
        float4 x = *(const float4*)(row + lane * 4 + i * 256);
        ss += x.x * x.x + x.y * x.y + x.z * x.z + x.w * x.w;
    }
#pragma unroll
    for (int off = 32; off > 0; off >>= 1) ss += __shfl_xor(ss, off, 64);
    if (lane == 0) invn[v] = 1.0f / sqrtf(ss);
}

// ---------------- bf16 MFMA GEMM + running approx top-4 per (row, colhalf) ----------------
// Block: 128 rows x 2048 cols (16 tiles of 128), K=1024, BK=32.
// 4 waves in 2x2; wave computes 64x64 via 4x4 grid of mfma_f32_16x16x32_bf16.
__global__ __launch_bounds__(256) void gemm_topk_kernel(
    const unsigned short* __restrict__ qbf, const unsigned short* __restrict__ sbf,
    const float* __restrict__ invn, float* __restrict__ pScore,
    int* __restrict__ pIdx) {
    __shared__ unsigned short As[BM * 32];   // 8 KB, row-major [128][32], swizzled chunks
    __shared__ unsigned short Bs[BN * 32];   // 8 KB
    __shared__ float Sc[BM * SCSTR];         // 34 KB score staging (64 cols/phase)
    __shared__ float invLds[BN];

    const int tid = threadIdx.x;
    const int l = tid & 63;
    const int w = tid >> 6;
    const int waveM = w >> 1;
    const int waveN = w & 1;
    const int rowBase = blockIdx.y * BM;
    const int colSplit = blockIdx.x;
    const int colStart = colSplit * COLS_PER_SPLIT;

    // staging: lane covers row l>>2 (of 16), 16B chunk l&3
    const int sRow = l >> 2;
    const int sChk = l & 3;
    // fragment read: m = l&15, k-chunk q = l>>4, swizzled position
    const int am = l & 15;
    const int q4 = l >> 4;
    const int cpos = (q4 ^ (l & 3) ^ ((l >> 2) & 3)) & 3;
    const int aFragOff = (waveM * 64 + am) * 64 + cpos * 16;   // bytes
    const int bFragOff = (waveN * 64 + am) * 64 + cpos * 16;

    char* AsB = (char*)As;
    char* BsB = (char*)Bs;
    char* ldsA0 = AsB + w * 1024;            // wave-uniform LDS bases
    char* ldsA1 = AsB + 4096 + w * 1024;
    char* ldsB0 = (char*)Bs + w * 1024;
    char* ldsB1 = (char*)Bs + 4096 + w * 1024;

    const int aRow0 = rowBase + w * 16 + sRow;
    const int aRow1 = aRow0 + 64;

    const int scanRow = tid >> 1;            // thread owns (row, col-bit5=sub)
    const int scanSub = tid & 1;
    float tv0 = -1e30f, tv1 = -1e30f, tv2 = -1e30f, tv3 = -1e30f;
    int ti0 = colStart, ti1 = colStart, ti2 = colStart, ti3 = colStart;

    for (int tile = 0; tile < TILES_PER_SPLIT; ++tile) {
        const int colBase = colStart + tile * BN;
        __syncthreads();                      // prev tile's scan fully done
        if (tid < BN) invLds[tid] = invn[colBase + tid];

        f32x4 acc[4][4];
#pragma unroll
        for (int i = 0; i < 4; ++i)
#pragma unroll
            for (int j = 0; j < 4; ++j) acc[i][j] = (f32x4)0.f;

        const int bRow0 = colBase + w * 16 + sRow;
        const int bRow1 = bRow0 + 64;

        for (int st = 0; st < 32; ++st) {
            const int kOff = st * 32 + sChk * 8;
            __syncthreads();                  // prev stage frag reads done
            GLDS16(qbf + ((size_t)aRow0 << 10) + kOff, ldsA0);
            GLDS16(qbf + ((size_t)aRow1 << 10) + kOff, ldsA1);
            GLDS16(sbf + ((size_t)bRow0 << 10) + kOff, ldsB0);
            GLDS16(sbf + ((size_t)bRow1 << 10) + kOff, ldsB1);
            __syncthreads();                  // staged data visible
            short8 af[4], bfr[4];
#pragma unroll
            for (int i = 0; i < 4; ++i)
                af[i] = *(const short8*)(AsB + aFragOff + i * 1024);
#pragma unroll
            for (int j = 0; j < 4; ++j)
                bfr[j] = *(const short8*)(BsB + bFragOff + j * 1024);
#pragma unroll
            for (int i = 0; i < 4; ++i)
#pragma unroll
                for (int j = 0; j < 4; ++j)
                    acc[i][j] = __builtin_amdgcn_mfma_f32_16x16x32_bf16(
                        af[i], bfr[j], acc[i][j], 0, 0, 0);
        }

        // score scan: two 64-col phases through Sc
#pragma unroll
        for (int h = 0; h < 2; ++h) {
            __syncthreads();                  // Sc free (prev readers done)
            if (waveN == h) {
#pragma unroll
                for (int i = 0; i < 4; ++i)
#pragma unroll
                    for (int j = 0; j < 4; ++j) {
                        const float iv = invLds[h * 64 + j * 16 + am];
                        const int scCol = j * 16 + am;
#pragma unroll
                        for (int r = 0; r < 4; ++r) {
                            const int scRow = waveM * 64 + i * 16 + q4 * 4 + r;
                            Sc[scRow * SCSTR + scCol] = acc[i][j][r] * iv;
                        }
                    }
            }
            __syncthreads();
            const int base = scanRow * SCSTR;
            for (int cc = 0; cc < 32; ++cc) {
                const int c = scanSub * 32 + ((cc + scanRow) & 31);  // skew: 2-way banks
                const float v = Sc[base + c];
                float mn = tv0; int mi = 0;
                if (tv1 < mn) { mn = tv1; mi = 1; }
                if (tv2 < mn) { mn = tv2; mi = 2; }
                if (tv3 < mn) { mn = tv3; mi = 3; }
                if (v > mn) {
                    const int idx = colBase + h * 64 + c;
                    if (mi == 0)      { tv0 = v; ti0 = idx; }
                    else if (mi == 1) { tv1 = v; ti1 = idx; }
                    else if (mi == 2) { tv2 = v; ti2 = idx; }
                    else              { tv3 = v; ti3 = idx; }
                }
            }
        }
    }

    const int prow = rowBase + scanRow;
    const size_t pbase = (((size_t)prow * CSPLIT + colSplit) * 2 + scanSub) * 4;
    pScore[pbase + 0] = tv0; pIdx[pbase + 0] = ti0;
    pScore[pbase + 1] = tv1; pIdx[pbase + 1] = ti1;
    pScore[pbase + 2] = tv2; pIdx[pbase + 2] = ti2;
    pScore[pbase + 3] = tv3; pIdx[pbase + 3] = ti3;
}

// ---------------- merge 256 partials -> approx top-16 -> exact rescore -> top-4 -> gather ----------------
__global__ __launch_bounds__(256) void merge_rescore_gather_kernel(
    const float* __restrict__ query, const float* __restrict__ synth,
    const float* __restrict__ invn, const float* __restrict__ pScore,
    const int* __restrict__ pIdx, float* __restrict__ out) {
    const int row = blockIdx.x;
    const int t = threadIdx.x;
    const int l = t & 63;
    const int w = t >> 6;
    __shared__ float sS[256];
    __shared__ int sI[256];
    __shared__ int candIdx[NCAND];
    __shared__ float candScore[NCAND];
    __shared__ int topIdx[KNN];

    sS[t] = pScore[(size_t)row * 256 + t];
    sI[t] = pIdx[(size_t)row * 256 + t];
    __syncthreads();
    const float mv = sS[t];
    int cnt = 0;
    for (int j = 0; j < 256; ++j) {          // broadcast reads, rank-by-count
        const float vj = sS[j];
        if (vj > mv || (vj == mv && j < t)) ++cnt;
    }
    if (cnt < NCAND) candIdx[cnt] = sI[t];   // ranks unique -> all 16 slots filled
    __syncthreads();

    // exact fp32 rescore: wave w handles candidates w*4 .. w*4+3
    const float* qrow = query + ((size_t)row << 10);
#pragma unroll
    for (int u = 0; u < NCAND / 4; ++u) {
        const int cand = w * (NCAND / 4) + u;
        const int sidx = candIdx[cand];
        const float* srow = synth + ((size_t)sidx << 10);
        float ss = 0.f;
#pragma unroll
        for (int i = 0; i < 4; ++i) {
            const float4 a = *(const float4*)(qrow + l * 4 + i * 256);
            const float4 b = *(const float4*)(srow + l * 4 + i * 256);
            ss += a.x * b.x + a.y * b.y + a.z * b.z + a.w * b.w;
        }
#pragma unroll
        for (int off = 32; off > 0; off >>= 1) ss += __shfl_xor(ss, off, 64);
        if (l == 0) candScore[cand] = ss * invn[sidx];
    }
    __syncthreads();
    if (t == 0) {
        float bv0 = -1e30f, bv1 = -1e30f, bv2 = -1e30f, bv3 = -1e30f;
        int bi0 = 0, bi1 = 0, bi2 = 0, bi3 = 0;
        for (int c = 0; c < NCAND; ++c) {
            const float v = candScore[c];
            float mn = bv0; int mi = 0;
            if (bv1 < mn) { mn = bv1; mi = 1; }
            if (bv2 < mn) { mn = bv2; mi = 2; }
            if (bv3 < mn) { mn = bv3; mi = 3; }
            if (v > mn) {
                const int idx = candIdx[c];
                if (mi == 0)      { bv0 = v; bi0 = idx; }
                else if (mi == 1) { bv1 = v; bi1 = idx; }
                else if (mi == 2) { bv2 = v; bi2 = idx; }
                else              { bv3 = v; bi3 = idx; }
            }
        }
        topIdx[0] = bi0; topIdx[1] = bi1; topIdx[2] = bi2; topIdx[3] = bi3;
    }
    __syncthreads();
    const int d = t * 4;
    float4 s = make_float4(0.f, 0.f, 0.f, 0.f);
#pragma unroll
    for (int m = 0; m < KNN; ++m) {
        const float4 x = *(const float4*)(synth + ((size_t)topIdx[m] << 10) + d);
        s.x += x.x; s.y += x.y; s.z += x.z; s.w += x.w;
    }
    s.x *= 0.25f; s.y *= 0.25f; s.z *= 0.25f; s.w *= 0.25f;
    *(float4*)(out + ((size_t)(2 * row) << 10) + d) = s;
    *(float4*)(out + ((size_t)(2 * row + 1) << 10) + d) = s;
}

// ================= round-1 fp32 fallback (used only if ws too small) =================
#define FB_BK 16
#define FB_LSTR 132
__global__ __launch_bounds__(256) void fb_score_topk_kernel(
    const float* __restrict__ query, const float* __restrict__ synth,
    const float* __restrict__ invn, float* __restrict__ pScore,
    int* __restrict__ pIdx) {
    __shared__ float As[FB_BK][FB_LSTR];
    __shared__ float Bs[FB_BK][FB_LSTR];
    __shared__ float Sc[BM][65];
    __shared__ float invLds[BN];
    const int tid = threadIdx.x;
    const int tx = tid & 15;
    const int ty = tid >> 4;
    const int rowBase = blockIdx.y * BM;
    const int colSplit = blockIdx.x;
    const int colStart = colSplit * COLS_PER_SPLIT;
    const int lr = tid >> 2;
    const int lk = (tid & 3) * 4;
    float tv0 = -1e30f, tv1 = -1e30f, tv2 = -1e30f, tv3 = -1e30f;
    int ti0 = 0, ti1 = 0, ti2 = 0, ti3 = 0;
    for (int tile = 0; tile < TILES_PER_SPLIT; ++tile) {
        const int colBase = colStart + tile * BN;
        float acc[8][8];
#pragma unroll
        for (int i = 0; i < 8; ++i)
#pragma unroll
            for (int j = 0; j < 8; ++j) acc[i][j] = 0.f;
        __syncthreads();
        if (tid < BN) invLds[tid] = invn[colBase + tid];
        for (int kk = 0; kk < DIM; kk += FB_BK) {
            float4 a0 = *(const float4*)(query + (size_t)(rowBase + lr) * DIM + kk + lk);
            float4 a1 = *(const float4*)(query + (size_t)(rowBase + lr + 64) * DIM + kk + lk);
            float4 b0 = *(const float4*)(synth + (size_t)(colBase + lr) * DIM + kk + lk);
            float4 b1 = *(const float4*)(synth + (size_t)(colBase + lr + 64) * DIM + kk + lk);
            __syncthreads();
            As[lk + 0][lr] = a0.x; As[lk + 1][lr] = a0.y;
            As[lk + 2][lr] = a0.z; As[lk + 3][lr] = a0.w;
            As[lk + 0][lr + 64] = a1.x; As[lk + 1][lr + 64] = a1.y;
            As[lk + 2][lr + 64] = a1.z; As[lk + 3][lr + 64] = a1.w;
            Bs[lk + 0][lr] = b0.x; Bs[lk + 1][lr] = b0.y;
            Bs[lk + 2][lr] = b0.z; Bs[lk + 3][lr] = b0.w;
            Bs[lk + 0][lr + 64] = b1.x; Bs[lk + 1][lr + 64] = b1.y;
            Bs[lk + 2][lr + 64] = b1.z; Bs[lk + 3][lr + 64] = b1.w;
            __syncthreads();
#pragma unroll
            for (int k = 0; k < FB_BK; ++k) {
                float ar[8], br[8];
                *(float4*)&ar[0] = *(const float4*)&As[k][ty * 8];
                *(float4*)&ar[4] = *(const float4*)&As[k][ty * 8 + 4];
                *(float4*)&br[0] = *(const float4*)&Bs[k][tx * 8];
                *(float4*)&br[4] = *(const float4*)&Bs[k][tx * 8 + 4];
#pragma unroll
                for (int i = 0; i < 8; ++i)
#pragma unroll
                    for (int j = 0; j < 8; ++j)
                        acc[i][j] = fmaf(ar[i], br[j], acc[i][j]);
            }
        }
#pragma unroll
        for (int h = 0; h < 2; ++h) {
            __syncthreads();
            if ((tx >> 3) == h) {
#pragma unroll
                for (int i = 0; i < 8; ++i)
#pragma unroll
                    for (int j = 0; j < 8; ++j)
                        Sc[ty * 8 + i][(tx & 7) * 8 + j] =
                            acc[i][j] * invLds[tx * 8 + j];
            }
            __syncthreads();
            if (tid < BM) {
                for (int c = 0; c < 64; ++c) {
                    const float v = Sc[tid][c];
                    float mn = tv0; int mi = 0;
                    if (tv1 < mn) { mn = tv1; mi = 1; }
                    if (tv2 < mn) { mn = tv2; mi = 2; }
                    if (tv3 < mn) { mn = tv3; mi = 3; }
                    if (v > mn) {
                        const int idx = colBase + h * 64 + c;
                        if (mi == 0)      { tv0 = v; ti0 = idx; }
                        else if (mi == 1) { tv1 = v; ti1 = idx; }
                        else if (mi == 2) { tv2 = v; ti2 = idx; }
                        else              { tv3 = v; ti3 = idx; }
                    }
                }
            }
        }
    }
    if (tid < BM) {
        const int row = rowBase + tid;
        const size_t base = ((size_t)row * CSPLIT + colSplit) * KNN;
        pScore[base + 0] = tv0; pIdx[base + 0] = ti0;
        pScore[base + 1] = tv1; pIdx[base + 1] = ti1;
        pScore[base + 2] = tv2; pIdx[base + 2] = ti2;
        pScore[base + 3] = tv3; pIdx[base + 3] = ti3;
    }
}

__global__ void fb_gather_kernel(const float* __restrict__ synth,
                                 const float* __restrict__ pScore,
                                 const int* __restrict__ pIdx,
                                 float* __restrict__ out) {
    const int row = blockIdx.x;
    __shared__ int sIdx[KNN];
    if (threadIdx.x == 0) {
        float bv0 = -1e30f, bv1 = -1e30f, bv2 = -1e30f, bv3 = -1e30f;
        int bi0 = 0, bi1 = 0, bi2 = 0, bi3 = 0;
        const float* ps = pScore + (size_t)row * CSPLIT * KNN;
        const int* pi = pIdx + (size_t)row * CSPLIT * KNN;
        for (int c = 0; c < CSPLIT * KNN; ++c) {
            const float v = ps[c];
            float mn = bv0; int mi = 0;
            if (bv1 < mn) { mn = bv1; mi = 1; }
            if (bv2 < mn) { mn = bv2; mi = 2; }
            if (bv3 < mn) { mn = bv3; mi = 3; }
            if (v > mn) {
                const int idx = pi[c];
                if (mi == 0)      { bv0 = v; bi0 = idx; }
                else if (mi == 1) { bv1 = v; bi1 = idx; }
                else if (mi == 2) { bv2 = v; bi2 = idx; }
                else              { bv3 = v; bi3 = idx; }
            }
        }
        sIdx[0] = bi0; sIdx[1] = bi1; sIdx[2] = bi2; sIdx[3] = bi3;
    }
    __syncthreads();
    const int d = threadIdx.x * 4;
    float4 s = make_float4(0.f, 0.f, 0.f, 0.f);
#pragma unroll
    for (int m = 0; m < KNN; ++m) {
        float4 x = *(const float4*)(synth + (size_t)sIdx[m] * DIM + d);
        s.x += x.x; s.y += x.y; s.z += x.z; s.w += x.w;
    }
    s.x *= 0.25f; s.y *= 0.25f; s.z *= 0.25f; s.w *= 0.25f;
    *(float4*)(out + (size_t)(2 * row) * DIM + d) = s;
    *(float4*)(out + (size_t)(2 * row + 1) * DIM + d) = s;
}

extern "C" void kernel_launch(void* const* d_in, const int* in_sizes, int n_in,
                              void* d_out, int out_size, void* d_ws, size_t ws_size,
                              hipStream_t stream) {
    const float* query = (const float*)d_in[0];   // (N1, DIM) fp32
    const float* synth = (const float*)d_in[1];   // (N2, DIM) fp32
    float* out = (float*)d_out;

    // fast-path ws layout
    const size_t SBF = (size_t)N2 * DIM * 2;                  // 134217728
    const size_t QBF = (size_t)N1 * DIM * 2;                  // 8388608
    const size_t INVN = (size_t)N2 * 4;                       // 262144
    const size_t PART = (size_t)N1 * CSPLIT * 2 * KNN * 4;    // 4194304
    const size_t NEED = SBF + QBF + INVN + 2 * PART;          // ~144 MB

    char* ws = (char*)d_ws;
    if (ws_size >= NEED) {
        unsigned short* sbf = (unsigned short*)ws;
        unsigned short* qbf = (unsigned short*)(ws + SBF);
        float* invn = (float*)(ws + SBF + QBF);
        float* pScore = (float*)(ws + SBF + QBF + INVN);
        int* pIdx = (int*)(ws + SBF + QBF + INVN + PART);

        convert_swz_kernel<<<(N2 * (DIM / 8)) / 256, 256, 0, stream>>>(synth, sbf);
        convert_swz_kernel<<<(N1 * (DIM / 8)) / 256, 256, 0, stream>>>(query, qbf);
        invnorm_kernel<<<N2 / 4, 256, 0, stream>>>(synth, invn);
        dim3 g1(CSPLIT, N1 / BM);
        gemm_topk_kernel<<<g1, 256, 0, stream>>>(qbf, sbf, invn, pScore, pIdx);
        merge_rescore_gather_kernel<<<N1, 256, 0, stream>>>(query, synth, invn,
                                                            pScore, pIdx, out);
    } else {
        float* invn = (float*)ws;
        float* pScore = (float*)(ws + INVN);
        int* pIdx = (int*)(ws + INVN + (size_t)N1 * CSPLIT * KNN * 4);
        invnorm_kernel<<<N2 / 4, 256, 0, stream>>>(synth, invn);
        dim3 g1(CSPLIT, N1 / BM);
        fb_score_topk_kernel<<<g1, 256, 0, stream>>>(query, synth, invn, pScore, pIdx);
        fb_gather_kernel<<<N1, 256, 0, stream>>>(synth, pScore, pIdx, out);
    }
}

// Round 3
// 1245.307 us; speedup vs baseline: 5.8866x; 1.1625x over previous
//
#include <hip/hip_runtime.h>
#include <math.h>
#include <stdint.h>

#define N1 4096
#define N2 65536
#define DIM 1024
#define KNN 4
#define CSPLIT 32
#define BM 128
#define BN 128
#define COLS_PER_SPLIT (N2 / CSPLIT)          // 2048
#define TILES_PER_SPLIT (COLS_PER_SPLIT / BN) // 16
#define NCAND 32
#define SCSTR 68                               // Sc stride (floats): 2-way banks

typedef __attribute__((ext_vector_type(8))) int int32x8;
typedef __attribute__((ext_vector_type(4))) float f32x4;

#define GLDS16(g, l)                                                          \
    __builtin_amdgcn_global_load_lds(                                         \
        (const __attribute__((address_space(1))) void*)(g),                   \
        (__attribute__((address_space(3))) void*)(l), 16, 0, 0)

// ---- fp32 -> fp8 e4m3fn (OCP), RNE, saturate to 448, subnormal-correct ----
__device__ __forceinline__ unsigned int f2fp8(float x) {
    const unsigned int u = __float_as_uint(x);
    const unsigned int s = (u >> 24) & 0x80u;
    const float ax = fminf(__uint_as_float(u & 0x7fffffffu), 448.f);
    int e = (int)(__float_as_uint(ax) >> 23) - 127;
    e = e < -6 ? -6 : e;
    const float q = rintf(ldexpf(ax, 3 - e));   // normals: [8,16]; subnorm: [0,8]
    return s | (unsigned int)((e + 6) * 8 + (int)q);  // q=16 carries into exponent
}

// ---------------- fp32 -> fp8 convert (+ fused 1/|row| for synth) ----------------
// Row = 1024 fp8 bytes = 64 16B-units. Within each 128B K-slice (8 units), unit u
// stores source unit u ^ ((row&3)<<1)  (32B-chunk XOR swizzle -> conflict-free-ish
// ds_read_b128 fragment reads after the forced-linear global_load_lds staging).
__global__ void convert_fp8_kernel(const float* __restrict__ src,
                                   uint8_t* __restrict__ dst,
                                   float* __restrict__ invn) {
    const int t = threadIdx.x;
    const int row = blockIdx.x * 32 + (t >> 3);
    const int u = t & 7;
    const int sw = (row & 3) << 1;
    const float* srow = src + ((size_t)row << 10);
    uint8_t* drow = dst + ((size_t)row << 10);
    float ss = 0.f;
#pragma unroll
    for (int k = 0; k < 8; ++k) {
        const float* p = srow + ((k * 8 + (u ^ sw)) << 4);
        unsigned int w[4];
#pragma unroll
        for (int g = 0; g < 4; ++g) {
            const float4 v = *(const float4*)(p + g * 4);
            ss += v.x * v.x + v.y * v.y + v.z * v.z + v.w * v.w;
            w[g] = f2fp8(v.x) | (f2fp8(v.y) << 8) | (f2fp8(v.z) << 16) |
                   (f2fp8(v.w) << 24);
        }
        *(uint4*)(drow + ((k * 8 + u) << 4)) = make_uint4(w[0], w[1], w[2], w[3]);
    }
#pragma unroll
    for (int off = 1; off < 8; off <<= 1) ss += __shfl_xor(ss, off, 64);
    if (invn != nullptr && u == 0) invn[row] = 1.0f / sqrtf(ss);
}

// ---------------- fp8 MFMA GEMM (K=128 scaled, scale==1.0) + running top-4 ----------------
// Block: 128 rows x 2048 cols (16 tiles of 128), K=1024, BK=128 -> 8 stages.
// 4 waves 2x2; wave = 64x64 via 4x4 grid of mfma_scale_f32_16x16x128_f8f6f4.
// LDS: As(16K)+Bs(16K) unioned with Sc(34816B) -> 35.3 KB total.
__global__ __launch_bounds__(256, 3) void gemm_topk_fp8(
    const uint8_t* __restrict__ qbf, const uint8_t* __restrict__ sbf,
    const float* __restrict__ invn, float* __restrict__ pScore,
    int* __restrict__ pIdx) {
    __shared__ __align__(16) char smem[BM * SCSTR * 4];  // 34816 B union
    __shared__ float invLds[BN];
    char* const AsB = smem;            // [128 rows][128 B] per stage
    char* const BsB = smem + 16384;
    float* const Sc = (float*)smem;

    const int tid = threadIdx.x;
    const int l = tid & 63;
    const int w = tid >> 6;
    const int waveM = w >> 1;
    const int waveN = w & 1;
    const int rowBase = blockIdx.y * BM;
    const int colSplit = blockIdx.x;
    const int colStart = colSplit * COLS_PER_SPLIT;

    // staging: wave w, instr i covers rows i*32 + w*8 .. +8 (lane l -> row +(l>>3), unit l&7)
    const uint8_t* aSrc =
        qbf + ((size_t)(rowBase + w * 8 + (l >> 3)) << 10) + (l & 7) * 16;
    const uint8_t* bSrc0 =
        sbf + ((size_t)(colStart + w * 8 + (l >> 3)) << 10) + (l & 7) * 16;
    char* const aDst = AsB + w * 1024;
    char* const bDst = BsB + w * 1024;

    // fragment read: m = l&15, K-chunk q4 = l>>4; stored chunk pos p = q4 ^ (row&3)
    const int am = l & 15;
    const int q4 = l >> 4;
    const int p = q4 ^ (am & 3);
    const int aOff = (waveM * 64 + am) * 128 + p * 32;   // + i*2048
    const int bOff = (waveN * 64 + am) * 128 + p * 32;   // + j*2048

    const unsigned int one_scales = 0x7f7f7f7fu;  // E8M0 127 -> x1.0 any byte

    const int scanRow = tid >> 1;
    const int scanSub = tid & 1;
    float tv0 = -1e30f, tv1 = -1e30f, tv2 = -1e30f, tv3 = -1e30f;
    int ti0 = colStart, ti1 = colStart, ti2 = colStart, ti3 = colStart;

    for (int tile = 0; tile < TILES_PER_SPLIT; ++tile) {
        const int colBase = colStart + tile * BN;
        const uint8_t* bSrc = bSrc0 + ((size_t)tile << 17);  // +tile*128*1024
        __syncthreads();                 // prev tile's Sc scan reads done
        if (tid < BN) invLds[tid] = invn[colBase + tid];

        f32x4 acc[4][4];
#pragma unroll
        for (int i = 0; i < 4; ++i)
#pragma unroll
            for (int j = 0; j < 4; ++j) acc[i][j] = (f32x4)0.f;

        for (int st = 0; st < 8; ++st) {
            const int kB = st * 128;
#pragma unroll
            for (int i = 0; i < 4; ++i)
                GLDS16(aSrc + (size_t)i * 32768 + kB, aDst + i * 4096);
#pragma unroll
            for (int i = 0; i < 4; ++i)
                GLDS16(bSrc + (size_t)i * 32768 + kB, bDst + i * 4096);
            __syncthreads();             // staged bytes visible (vmcnt0 drain)
            int32x8 af[4], bf[4];
#pragma unroll
            for (int i = 0; i < 4; ++i)
                af[i] = *(const int32x8*)(AsB + aOff + i * 2048);
#pragma unroll
            for (int j = 0; j < 4; ++j)
                bf[j] = *(const int32x8*)(BsB + bOff + j * 2048);
#pragma unroll
            for (int i = 0; i < 4; ++i)
#pragma unroll
                for (int j = 0; j < 4; ++j)
                    acc[i][j] = __builtin_amdgcn_mfma_scale_f32_16x16x128_f8f6f4(
                        af[i], bf[j], acc[i][j], 0, 0,   // cbsz=0 (e4m3), blgp=0
                        0, one_scales, 0, one_scales);   // opsel,scaleA, opsel,scaleB
            __syncthreads();             // frag reads drained before overwrite
        }

        // epilogue: scores x invnorm through Sc (aliases As/Bs - K-loop done)
#pragma unroll
        for (int h = 0; h < 2; ++h) {
            if (waveN == h) {
#pragma unroll
                for (int i = 0; i < 4; ++i)
#pragma unroll
                    for (int j = 0; j < 4; ++j) {
                        const float iv = invLds[h * 64 + j * 16 + am];
                        const int scCol = j * 16 + am;
#pragma unroll
                        for (int r = 0; r < 4; ++r) {
                            const int scRow = waveM * 64 + i * 16 + q4 * 4 + r;
                            Sc[scRow * SCSTR + scCol] = acc[i][j][r] * iv;
                        }
                    }
            }
            __syncthreads();
            const int base = scanRow * SCSTR;
            for (int cc = 0; cc < 32; ++cc) {
                const int c = scanSub * 32 + ((cc + scanRow) & 31);
                const float v = Sc[base + c];
                float mn = tv0; int mi = 0;
                if (tv1 < mn) { mn = tv1; mi = 1; }
                if (tv2 < mn) { mn = tv2; mi = 2; }
                if (tv3 < mn) { mn = tv3; mi = 3; }
                if (v > mn) {
                    const int idx = colBase + h * 64 + c;
                    if (mi == 0)      { tv0 = v; ti0 = idx; }
                    else if (mi == 1) { tv1 = v; ti1 = idx; }
                    else if (mi == 2) { tv2 = v; ti2 = idx; }
                    else              { tv3 = v; ti3 = idx; }
                }
            }
            if (h == 0) __syncthreads();  // scan reads done before h=1 Sc writes
        }
    }

    const int prow = rowBase + scanRow;
    const size_t pbase = (((size_t)prow * CSPLIT + colSplit) * 2 + scanSub) * 4;
    pScore[pbase + 0] = tv0; pIdx[pbase + 0] = ti0;
    pScore[pbase + 1] = tv1; pIdx[pbase + 1] = ti1;
    pScore[pbase + 2] = tv2; pIdx[pbase + 2] = ti2;
    pScore[pbase + 3] = tv3; pIdx[pbase + 3] = ti3;
}

// ------- merge 256 partials -> approx top-32 -> exact fp32 rescore -> top-4 -> gather -------
__global__ __launch_bounds__(256) void merge_rescore_gather_kernel(
    const float* __restrict__ query, const float* __restrict__ synth,
    const float* __restrict__ invn, const float* __restrict__ pScore,
    const int* __restrict__ pIdx, float* __restrict__ out) {
    const int row = blockIdx.x;
    const int t = threadIdx.x;
    const int l = t & 63;
    const int w = t >> 6;
    __shared__ float sS[256];
    __shared__ int sI[256];
    __shared__ int candIdx[NCAND];
    __shared__ float candScore[NCAND];
    __shared__ int topIdx[KNN];

    sS[t] = pScore[(size_t)row * 256 + t];
    sI[t] = pIdx[(size_t)row * 256 + t];
    __syncthreads();
    const float mv = sS[t];
    int cnt = 0;
    for (int j = 0; j < 256; ++j) {
        const float vj = sS[j];
        if (vj > mv || (vj == mv && j < t)) ++cnt;
    }
    if (cnt < NCAND) candIdx[cnt] = sI[t];
    __syncthreads();

    const float* qrow = query + ((size_t)row << 10);
#pragma unroll
    for (int u = 0; u < NCAND / 4; ++u) {
        const int cand = w * (NCAND / 4) + u;
        const int sidx = candIdx[cand];
        const float* srow = synth + ((size_t)sidx << 10);
        float ss = 0.f;
#pragma unroll
        for (int i = 0; i < 4; ++i) {
            const float4 a = *(const float4*)(qrow + l * 4 + i * 256);
            const float4 b = *(const float4*)(srow + l * 4 + i * 256);
            ss += a.x * b.x + a.y * b.y + a.z * b.z + a.w * b.w;
        }
#pragma unroll
        for (int off = 32; off > 0; off >>= 1) ss += __shfl_xor(ss, off, 64);
        if (l == 0) candScore[cand] = ss * invn[sidx];
    }
    __syncthreads();
    if (t == 0) {
        float bv0 = -1e30f, bv1 = -1e30f, bv2 = -1e30f, bv3 = -1e30f;
        int bi0 = 0, bi1 = 0, bi2 = 0, bi3 = 0;
        for (int c = 0; c < NCAND; ++c) {
            const float v = candScore[c];
            float mn = bv0; int mi = 0;
            if (bv1 < mn) { mn = bv1; mi = 1; }
            if (bv2 < mn) { mn = bv2; mi = 2; }
            if (bv3 < mn) { mn = bv3; mi = 3; }
            if (v > mn) {
                const int idx = candIdx[c];
                if (mi == 0)      { bv0 = v; bi0 = idx; }
                else if (mi == 1) { bv1 = v; bi1 = idx; }
                else if (mi == 2) { bv2 = v; bi2 = idx; }
                else              { bv3 = v; bi3 = idx; }
            }
        }
        topIdx[0] = bi0; topIdx[1] = bi1; topIdx[2] = bi2; topIdx[3] = bi3;
    }
    __syncthreads();
    const int d = t * 4;
    float4 s = make_float4(0.f, 0.f, 0.f, 0.f);
#pragma unroll
    for (int m = 0; m < KNN; ++m) {
        const float4 x = *(const float4*)(synth + ((size_t)topIdx[m] << 10) + d);
        s.x += x.x; s.y += x.y; s.z += x.z; s.w += x.w;
    }
    s.x *= 0.25f; s.y *= 0.25f; s.z *= 0.25f; s.w *= 0.25f;
    *(float4*)(out + ((size_t)(2 * row) << 10) + d) = s;
    *(float4*)(out + ((size_t)(2 * row + 1) << 10) + d) = s;
}

extern "C" void kernel_launch(void* const* d_in, const int* in_sizes, int n_in,
                              void* d_out, int out_size, void* d_ws, size_t ws_size,
                              hipStream_t stream) {
    const float* query = (const float*)d_in[0];   // (N1, DIM) fp32
    const float* synth = (const float*)d_in[1];   // (N2, DIM) fp32
    float* out = (float*)d_out;

    char* ws = (char*)d_ws;
    const size_t S8 = (size_t)N2 * DIM;           // 67108864
    const size_t Q8 = (size_t)N1 * DIM;           // 4194304
    const size_t INVN = (size_t)N2 * 4;           // 262144
    const size_t PART = (size_t)N1 * 256 * 4;     // 4194304
    uint8_t* sbf = (uint8_t*)ws;
    uint8_t* qbf = (uint8_t*)(ws + S8);
    float* invn = (float*)(ws + S8 + Q8);
    float* pScore = (float*)(ws + S8 + Q8 + INVN);
    int* pIdx = (int*)(ws + S8 + Q8 + INVN + PART);

    convert_fp8_kernel<<<N2 / 32, 256, 0, stream>>>(synth, sbf, invn);
    convert_fp8_kernel<<<N1 / 32, 256, 0, stream>>>(query, qbf, nullptr);
    dim3 g1(CSPLIT, N1 / BM);
    gemm_topk_fp8<<<g1, 256, 0, stream>>>(qbf, sbf, invn, pScore, pIdx);
    merge_rescore_gather_kernel<<<N1, 256, 0, stream>>>(query, synth, invn,
                                                        pScore, pIdx, out);
}